// Round 2
// baseline (1043.716 us; speedup 1.0000x reference)
//
#include <hip/hip_runtime.h>
#include <stdint.h>

// Problem dims
#define MROWS 32768   // B*T
#define TSEQ  1024
#define BBATCH 32
#define INDIM 1536
#define DDIM  768
#define NCAT  2304    // un_emb (768) + pw_x (768) + pw_y (768)

typedef short short8 __attribute__((ext_vector_type(8)));
typedef float f32x4  __attribute__((ext_vector_type(4)));

__device__ __forceinline__ float b2f(ushort u) {
    union { uint32_t u; float f; } x; x.u = ((uint32_t)u) << 16; return x.f;
}
__device__ __forceinline__ ushort f2b(float f) {
    union { float f; uint32_t u; } x; x.f = f;
    uint32_t r = x.u + 0x7fffu + ((x.u >> 16) & 1u);
    return (ushort)(r >> 16);
}

// ---------------- fp32 -> bf16 conversion (vectorized x4) ----------------
__global__ void cvt_bf16(const float* __restrict__ in, ushort* __restrict__ out, int n4) {
    int i = blockIdx.x * blockDim.x + threadIdx.x;
    if (i < n4) {
        float4 v = ((const float4*)in)[i];
        ushort4 o;
        o.x = f2b(v.x); o.y = f2b(v.y); o.z = f2b(v.z); o.w = f2b(v.w);
        ((ushort4*)out)[i] = o;
    }
}

__device__ __forceinline__ void cvt4(const float* __restrict__ in, ushort* __restrict__ out, int i) {
    float4 v = ((const float4*)in)[i];
    ushort4 o;
    o.x = f2b(v.x); o.y = f2b(v.y); o.z = f2b(v.z); o.w = f2b(v.w);
    ((ushort4*)out)[i] = o;
}

// All small weight conversions + bias concat in ONE launch.
__global__ void cvt_weights(const float* __restrict__ fc1_w, const float* __restrict__ fc2_w,
                            const float* __restrict__ w3a, const float* __restrict__ w3b,
                            const float* __restrict__ w3c,
                            const float* __restrict__ ba, const float* __restrict__ bb,
                            const float* __restrict__ bc,
                            ushort* __restrict__ W1, ushort* __restrict__ W2,
                            ushort* __restrict__ W3, float* __restrict__ B3)
{
    int i = blockIdx.x * 256 + threadIdx.x;  // float4 index
    if (i < 589824)        cvt4(fc1_w, W1, i);
    else if (i < 884736)   cvt4(fc2_w, W2, i - 589824);
    else if (i < 1032192)  cvt4(w3a,  W3,           i - 884736);
    else if (i < 1179648)  cvt4(w3b,  W3 + 589824,  i - 1032192);
    else if (i < 1327104)  cvt4(w3c,  W3 + 1179648, i - 1179648);
    else if (i < 1327680) {
        int j = i - 1327104;  // 0..575 float4s of B3 (2304 floats)
        const float* src = (j < 192) ? ba : (j < 384) ? bb : bc;
        int off = (j < 192) ? j : (j < 384) ? (j - 192) : (j - 384);
        ((float4*)B3)[j] = ((const float4*)src)[off];
    }
}

// ---------------- bf16 GEMM: C[M,N] = A[M,K] * B[N,K]^T + bias, optional relu on cols < relu_ncols
// 128x128 tile / block, 4 waves (2x2), each wave 64x64 = 4x4 MFMA 16x16x32 subtiles.
// global_load_lds width=16 staging. LDS stored fragment-order (col-block-major per
// 16-row segment) so each ds_read_b128 across the wave touches a contiguous 1 KiB
// -> zero bank conflicts. blockIdx.x = n (fastest) so consecutive blocks share the
// A-tile (L2/LLC reuse). Requires M%128==0, N%128==0, K%32==0.
__global__ __launch_bounds__(256, 2)
void gemm_bt(const ushort* __restrict__ A, const ushort* __restrict__ Bm,
             const float* __restrict__ bias, ushort* __restrict__ C,
             int M, int N, int K, int relu_ncols)
{
    __shared__ __align__(16) ushort lA[128 * 32];  // 8 KB, 8 segments of 16x32
    __shared__ __align__(16) ushort lB[128 * 32];  // 8 KB

    const int tid  = threadIdx.x;
    const int lane = tid & 63, wave = tid >> 6;
    const int wm = wave & 1, wn = wave >> 1;       // 2x2 wave grid
    const int quad = lane >> 4, r16 = lane & 15;
    const int m0 = blockIdx.y * 128, n0 = blockIdx.x * 128;
    // staging lane->global map chosen so LDS (base + lane*16B) lands fragment-order:
    // lane covers global (row = lane&15, colblock = lane>>4) of its 16x32 segment.
    const int srow = lane & 15;
    const int scol = (lane >> 4) * 8;

    f32x4 acc[4][4] = {};

    const int kIters = K >> 5;
    for (int kt = 0; kt < kIters; ++kt) {
        const int k0 = kt << 5;
        __syncthreads();   // previous iteration's LDS reads complete
#pragma unroll
        for (int c = 0; c < 2; ++c) {
            int seg = wave * 2 + c;
            int row = seg * 16 + srow;
            const ushort* ga = A + (size_t)(m0 + row) * K + k0 + scol;
            __builtin_amdgcn_global_load_lds(
                (const __attribute__((address_space(1))) void*)ga,
                (__attribute__((address_space(3))) void*)&lA[seg * 512], 16, 0, 0);
            const ushort* gb = Bm + (size_t)(n0 + row) * K + k0 + scol;
            __builtin_amdgcn_global_load_lds(
                (const __attribute__((address_space(1))) void*)gb,
                (__attribute__((address_space(3))) void*)&lB[seg * 512], 16, 0, 0);
        }
        __syncthreads();   // staging complete

        short8 af[4], bf[4];
#pragma unroll
        for (int i = 0; i < 4; ++i)   // seg = wm*4+i, fragment (quad,r16) at (quad*16+r16)*8
            af[i] = *(const short8*)&lA[(wm * 4 + i) * 512 + (quad * 16 + r16) * 8];
#pragma unroll
        for (int j = 0; j < 4; ++j)
            bf[j] = *(const short8*)&lB[(wn * 4 + j) * 512 + (quad * 16 + r16) * 8];
#pragma unroll
        for (int i = 0; i < 4; ++i)
#pragma unroll
            for (int j = 0; j < 4; ++j)
                acc[i][j] = __builtin_amdgcn_mfma_f32_16x16x32_bf16(af[i], bf[j], acc[i][j], 0, 0, 0);
    }

    // epilogue: C/D layout col = lane&15, row = quad*4 + reg  [m89-verified]
#pragma unroll
    for (int j = 0; j < 4; ++j) {
        int gn = n0 + wn * 64 + j * 16 + r16;
        float bv = bias[gn];
        bool dorelu = gn < relu_ncols;
#pragma unroll
        for (int i = 0; i < 4; ++i) {
            int gmb = m0 + wm * 64 + i * 16 + quad * 4;
#pragma unroll
            for (int rr = 0; rr < 4; ++rr) {
                float v = acc[i][j][rr] + bv;
                if (dorelu) v = fmaxf(v, 0.f);
                C[(size_t)(gmb + rr) * N + gn] = f2b(v);
            }
        }
    }
}

// ---------------- per-row stats over G3=[M,2304] (e | xe | ye), bf16 ----------------
// un_pot[m] = sum(e*urw)+urb ; rnx[m]=1/||xe|| ; rny[m]=1/||ye||
__global__ void row_stats_k(const ushort* __restrict__ G3, const float* __restrict__ urw,
                            const float* __restrict__ urb, float* __restrict__ un_pot,
                            float* __restrict__ rnx, float* __restrict__ rny)
{
    int m = blockIdx.x, tid = threadIdx.x;
    const ushort* row = G3 + (size_t)m * NCAT;
    float se = 0.f, sx = 0.f, sy = 0.f;
    for (int t = tid; t < DDIM; t += 256) {
        float ev = b2f(row[t]);          se += ev * urw[t];
        float xv = b2f(row[DDIM + t]);   sx += xv * xv;
        float yv = b2f(row[2*DDIM + t]); sy += yv * yv;
    }
    for (int off = 32; off; off >>= 1) {
        se += __shfl_down(se, off, 64);
        sx += __shfl_down(sx, off, 64);
        sy += __shfl_down(sy, off, 64);
    }
    __shared__ float rb[3][4];
    int lane = tid & 63, w = tid >> 6;
    if (lane == 0) { rb[0][w] = se; rb[1][w] = sx; rb[2][w] = sy; }
    __syncthreads();
    if (tid == 0) {
        float a = rb[0][0] + rb[0][1] + rb[0][2] + rb[0][3];
        float nx = sqrtf(rb[1][0] + rb[1][1] + rb[1][2] + rb[1][3]);
        float ny = sqrtf(rb[2][0] + rb[2][1] + rb[2][2] + rb[2][3]);
        un_pot[m] = a + urb[0];
        rnx[m] = 1.f / fmaxf(nx, 1e-12f);
        rny[m] = 1.f / fmaxf(ny, 1e-12f);
    }
}

// ---------------- ybar[b,d] += partial over a 64-step s chunk ----------------
// ybar[b,d] = (1/T) * sum_s ye[b,s,d] * rny[b,s]; grid (B, 16), 256 thr, 3 d/thread.
__global__ void ybar_k(const ushort* __restrict__ G3, const float* __restrict__ rny,
                       float* __restrict__ ybar)
{
    int b = blockIdx.x, s0 = blockIdx.y * 64;
    int tid = threadIdx.x;
    __shared__ float sr[64];
    if (tid < 64) sr[tid] = rny[b * TSEQ + s0 + tid] * (1.0f / TSEQ);
    __syncthreads();
    float a0 = 0.f, a1 = 0.f, a2 = 0.f;
    for (int s = 0; s < 64; ++s) {
        const ushort* row = G3 + (size_t)(b * TSEQ + s0 + s) * NCAT + 2 * DDIM;
        float w = sr[s];
        a0 += b2f(row[tid])       * w;
        a1 += b2f(row[tid + 256]) * w;
        a2 += b2f(row[tid + 512]) * w;
    }
    atomicAdd(&ybar[b * DDIM + tid],       a0);
    atomicAdd(&ybar[b * DDIM + tid + 256], a1);
    atomicAdd(&ybar[b * DDIM + tid + 512], a2);
}

// ---------------- scores[m] = rw0*un_pot + rw1 * rnx[m]*dot(xe[m], ybar[b]) ----------------
__global__ void pw_scores_k(const ushort* __restrict__ G3, const float* __restrict__ ybar,
                            const float* __restrict__ rnx, const float* __restrict__ un_pot,
                            const float* __restrict__ red_w, float* __restrict__ scores)
{
    int m = blockIdx.x, tid = threadIdx.x;
    int b = m >> 10;
    const ushort* xer = G3 + (size_t)m * NCAT + DDIM;
    const float* yb = ybar + b * DDIM;
    float s = 0.f;
    for (int t = tid; t < DDIM; t += 256) s += b2f(xer[t]) * yb[t];
    for (int off = 32; off; off >>= 1) s += __shfl_down(s, off, 64);
    __shared__ float rb[4];
    int lane = tid & 63, w = tid >> 6;
    if (lane == 0) rb[w] = s;
    __syncthreads();
    if (tid == 0) {
        float dot = rb[0] + rb[1] + rb[2] + rb[3];
        scores[m] = red_w[0] * un_pot[m] + red_w[1] * (rnx[m] * dot);
    }
}

// ---------------- softmax over T per batch ----------------
__global__ void softmax_k(const float* __restrict__ scores, float* __restrict__ wsm)
{
    int b = blockIdx.x, tid = threadIdx.x;
    float v[4];
    float lm = -1e30f;
#pragma unroll
    for (int i = 0; i < 4; ++i) {
        v[i] = scores[b * TSEQ + i * 256 + tid];
        lm = fmaxf(lm, v[i]);
    }
    for (int off = 32; off; off >>= 1) lm = fmaxf(lm, __shfl_down(lm, off, 64));
    __shared__ float rb[4];
    __shared__ float smax, ssum;
    int lane = tid & 63, w = tid >> 6;
    if (lane == 0) rb[w] = lm;
    __syncthreads();
    if (tid == 0) smax = fmaxf(fmaxf(rb[0], rb[1]), fmaxf(rb[2], rb[3]));
    __syncthreads();
    float e[4];
    float ls = 0.f;
#pragma unroll
    for (int i = 0; i < 4; ++i) { e[i] = expf(v[i] - smax); ls += e[i]; }
    for (int off = 32; off; off >>= 1) ls += __shfl_down(ls, off, 64);
    __syncthreads();
    if (lane == 0) rb[w] = ls;
    __syncthreads();
    if (tid == 0) ssum = rb[0] + rb[1] + rb[2] + rb[3];
    __syncthreads();
    float inv = 1.f / ssum;
#pragma unroll
    for (int i = 0; i < 4; ++i) wsm[b * TSEQ + i * 256 + tid] = e[i] * inv;
}

// ---------------- out[b,d] += partial over a 64-step t chunk ----------------
__global__ void out_k(const ushort* __restrict__ U16, const float* __restrict__ wsm,
                      float* __restrict__ out)
{
    int b = blockIdx.x, t0 = blockIdx.y * 64;
    int tid = threadIdx.x;
    __shared__ float sw[64];
    if (tid < 64) sw[tid] = wsm[b * TSEQ + t0 + tid];
    __syncthreads();
    float a0 = 0.f, a1 = 0.f, a2 = 0.f;
    for (int t = 0; t < 64; ++t) {
        const ushort* row = U16 + (size_t)(b * TSEQ + t0 + t) * DDIM;
        float w = sw[t];
        a0 += b2f(row[tid])       * w;
        a1 += b2f(row[tid + 256]) * w;
        a2 += b2f(row[tid + 512]) * w;
    }
    atomicAdd(&out[b * DDIM + tid],       a0);
    atomicAdd(&out[b * DDIM + tid + 256], a1);
    atomicAdd(&out[b * DDIM + tid + 512], a2);
}

// ---------------- workspace layout (bytes) ----------------
// G3 (e|xe|ye bf16, 151 MB) aliases the X16+H16 region (dead after GEMM2).
static const size_t O_X16   = 0;            // 32768*1536*2 = 100663296
static const size_t O_H16   = 100663296;    // 100663296
static const size_t O_G3    = 0;            // 150994944 (alias)
static const size_t O_U16   = 201326592;    // 50331648
static const size_t O_W1    = 251658240;    // 4718592
static const size_t O_W2    = 256376832;    // 2359296
static const size_t O_W3    = 258736128;    // 3538944
static const size_t O_B3    = 262275072;    // 9216
static const size_t O_UNPOT = 262284288;    // 131072
static const size_t O_RNX   = 262415360;    // 131072
static const size_t O_RNY   = 262546432;    // 131072
static const size_t O_SCORE = 262677504;    // 131072
static const size_t O_WSM   = 262808576;    // 131072
static const size_t O_YBAR  = 262939648;    // 98304
// total: 263037952 bytes (~263 MB)

extern "C" void kernel_launch(void* const* d_in, const int* in_sizes, int n_in,
                              void* d_out, int out_size, void* d_ws, size_t ws_size,
                              hipStream_t stream)
{
    const float* x        = (const float*)d_in[0];
    const float* fc1_w    = (const float*)d_in[1];
    const float* fc1_b    = (const float*)d_in[2];
    const float* fc2_w    = (const float*)d_in[3];
    const float* fc2_b    = (const float*)d_in[4];
    const float* un_emb_w = (const float*)d_in[5];
    const float* un_emb_b = (const float*)d_in[6];
    const float* un_red_w = (const float*)d_in[7];
    const float* un_red_b = (const float*)d_in[8];
    const float* pw_x_w   = (const float*)d_in[9];
    const float* pw_x_b   = (const float*)d_in[10];
    const float* pw_y_w   = (const float*)d_in[11];
    const float* pw_y_b   = (const float*)d_in[12];
    const float* red_w    = (const float*)d_in[13];

    char* ws = (char*)d_ws;
    ushort* X16 = (ushort*)(ws + O_X16);
    ushort* H16 = (ushort*)(ws + O_H16);
    ushort* G3  = (ushort*)(ws + O_G3);
    ushort* U16 = (ushort*)(ws + O_U16);
    ushort* W1  = (ushort*)(ws + O_W1);
    ushort* W2  = (ushort*)(ws + O_W2);
    ushort* W3  = (ushort*)(ws + O_W3);
    float*  B3  = (float*)(ws + O_B3);
    float*  UNPOT = (float*)(ws + O_UNPOT);
    float*  RNX = (float*)(ws + O_RNX);
    float*  RNY = (float*)(ws + O_RNY);
    float*  SCORES = (float*)(ws + O_SCORE);
    float*  WSM = (float*)(ws + O_WSM);
    float*  YBAR = (float*)(ws + O_YBAR);

    // --- zero the atomic accumulators (ws/d_out are poisoned 0xAA each call) ---
    hipMemsetAsync(YBAR, 0, BBATCH * DDIM * sizeof(float), stream);
    hipMemsetAsync(d_out, 0, BBATCH * DDIM * sizeof(float), stream);

    // --- convert inputs to bf16 ---
    cvt_bf16<<<49152, 256, 0, stream>>>(x, X16, 12582912);   // 32768*1536/4
    cvt_weights<<<5187, 256, 0, stream>>>(fc1_w, fc2_w, un_emb_w, pw_x_w, pw_y_w,
                                          un_emb_b, pw_x_b, pw_y_b, W1, W2, W3, B3);

    // --- GEMM chain (blockIdx.x = n for A-tile L2 reuse) ---
    // h = relu(x @ fc1_w^T + fc1_b)            [M,1536]
    gemm_bt<<<dim3(INDIM / 128, MROWS / 128), 256, 0, stream>>>(
        X16, W1, fc1_b, H16, MROWS, INDIM, INDIM, INDIM);
    // u = h @ fc2_w^T + fc2_b                  [M,768]
    gemm_bt<<<dim3(DDIM / 128, MROWS / 128), 256, 0, stream>>>(
        H16, W2, fc2_b, U16, MROWS, DDIM, INDIM, 0);
    // [e|xe|ye] = u @ [un_emb|pw_x|pw_y]^T + b  [M,2304], relu on first 768 cols (e)
    gemm_bt<<<dim3(NCAT / 128, MROWS / 128), 256, 0, stream>>>(
        U16, W3, B3, G3, MROWS, NCAT, DDIM, DDIM);

    // --- reductions / attention ---
    row_stats_k<<<MROWS, 256, 0, stream>>>(G3, un_red_w, un_red_b, UNPOT, RNX, RNY);
    ybar_k<<<dim3(BBATCH, 16), 256, 0, stream>>>(G3, RNY, YBAR);
    pw_scores_k<<<MROWS, 256, 0, stream>>>(G3, YBAR, RNX, UNPOT, red_w, SCORES);
    softmax_k<<<BBATCH, 256, 0, stream>>>(SCORES, WSM);
    out_k<<<dim3(BBATCH, 16), 256, 0, stream>>>(U16, WSM, (float*)d_out);
}

// Round 3
// 1030.591 us; speedup vs baseline: 1.0127x; 1.0127x over previous
//
#include <hip/hip_runtime.h>
#include <stdint.h>

// Problem dims
#define MROWS 32768   // B*T
#define TSEQ  1024
#define BBATCH 32
#define INDIM 1536
#define DDIM  768
#define NCAT  2304    // un_emb (768) + pw_x (768) + pw_y (768)

typedef short short8 __attribute__((ext_vector_type(8)));
typedef float f32x4  __attribute__((ext_vector_type(4)));

__device__ __forceinline__ float b2f(ushort u) {
    union { uint32_t u; float f; } x; x.u = ((uint32_t)u) << 16; return x.f;
}
__device__ __forceinline__ ushort f2b(float f) {
    union { float f; uint32_t u; } x; x.f = f;
    uint32_t r = x.u + 0x7fffu + ((x.u >> 16) & 1u);
    return (ushort)(r >> 16);
}

// ---------------- fp32 -> bf16 conversion (vectorized x4) ----------------
__global__ void cvt_bf16(const float* __restrict__ in, ushort* __restrict__ out, int n4) {
    int i = blockIdx.x * blockDim.x + threadIdx.x;
    if (i < n4) {
        float4 v = ((const float4*)in)[i];
        ushort4 o;
        o.x = f2b(v.x); o.y = f2b(v.y); o.z = f2b(v.z); o.w = f2b(v.w);
        ((ushort4*)out)[i] = o;
    }
}

__device__ __forceinline__ void cvt4(const float* __restrict__ in, ushort* __restrict__ out, int i) {
    float4 v = ((const float4*)in)[i];
    ushort4 o;
    o.x = f2b(v.x); o.y = f2b(v.y); o.z = f2b(v.z); o.w = f2b(v.w);
    ((ushort4*)out)[i] = o;
}

// All small weight conversions + bias concat in ONE launch.
__global__ void cvt_weights(const float* __restrict__ fc1_w, const float* __restrict__ fc2_w,
                            const float* __restrict__ w3a, const float* __restrict__ w3b,
                            const float* __restrict__ w3c,
                            const float* __restrict__ ba, const float* __restrict__ bb,
                            const float* __restrict__ bc,
                            ushort* __restrict__ W1, ushort* __restrict__ W2,
                            ushort* __restrict__ W3, float* __restrict__ B3)
{
    int i = blockIdx.x * 256 + threadIdx.x;  // float4 index
    if (i < 589824)        cvt4(fc1_w, W1, i);
    else if (i < 884736)   cvt4(fc2_w, W2, i - 589824);
    else if (i < 1032192)  cvt4(w3a,  W3,           i - 884736);
    else if (i < 1179648)  cvt4(w3b,  W3 + 589824,  i - 1032192);
    else if (i < 1327104)  cvt4(w3c,  W3 + 1179648, i - 1179648);
    else if (i < 1327680) {
        int j = i - 1327104;  // 0..575 float4s of B3 (2304 floats)
        const float* src = (j < 192) ? ba : (j < 384) ? bb : bc;
        int off = (j < 192) ? j : (j < 384) ? (j - 192) : (j - 384);
        ((float4*)B3)[j] = ((const float4*)src)[off];
    }
}

// ---------------- bf16 GEMM: C[M,N] = A[M,K] * B[N,K]^T + bias, optional relu on cols < relu_ncols
// 128x128 tile / block, 4 waves (2x2), each wave 64x64 = 4x4 MFMA 16x16x32 subtiles.
// global_load_lds width=16 staging; LDS stored fragment-order (zero bank conflicts).
// XCD-pinned swizzle: blocks round-robin XCDs by blockIdx%8, so we put all ntiles
// consumers of one A-tile consecutively on ONE XCD -> A-tile is fetched into that
// XCD's L2 once and reused ntiles times at L2 latency (round-2 showed cross-XCD
// reuse via LLC costs ~85us on GEMM1). Requires (M/128)%8==0, N%128==0, K%32==0.
__global__ __launch_bounds__(256, 2)
void gemm_bt(const ushort* __restrict__ A, const ushort* __restrict__ Bm,
             const float* __restrict__ bias, ushort* __restrict__ C,
             int M, int N, int K, int relu_ncols)
{
    __shared__ __align__(16) ushort lA[128 * 32];  // 8 KB, 8 segments of 16x32
    __shared__ __align__(16) ushort lB[128 * 32];  // 8 KB

    const int tid  = threadIdx.x;
    const int lane = tid & 63, wave = tid >> 6;
    const int wm = wave & 1, wn = wave >> 1;       // 2x2 wave grid
    const int quad = lane >> 4, r16 = lane & 15;

    // XCD-pinned block swizzle
    const int ntiles = N >> 7;
    const int xcd = blockIdx.x & 7;
    const int j   = blockIdx.x >> 3;
    const int g   = j / ntiles;            // m-group within this XCD
    const int n_t = j - g * ntiles;
    const int m_t = xcd + (g << 3);
    const int m0 = m_t * 128, n0 = n_t * 128;

    // staging lane->global map chosen so LDS (base + lane*16B) lands fragment-order:
    // lane covers global (row = lane&15, colblock = lane>>4) of its 16x32 segment.
    const int srow = lane & 15;
    const int scol = (lane >> 4) * 8;

    f32x4 acc[4][4] = {};

    const int kIters = K >> 5;
    for (int kt = 0; kt < kIters; ++kt) {
        const int k0 = kt << 5;
        __syncthreads();   // previous iteration's LDS reads complete
#pragma unroll
        for (int c = 0; c < 2; ++c) {
            int seg = wave * 2 + c;
            int row = seg * 16 + srow;
            const ushort* ga = A + (size_t)(m0 + row) * K + k0 + scol;
            __builtin_amdgcn_global_load_lds(
                (const __attribute__((address_space(1))) void*)ga,
                (__attribute__((address_space(3))) void*)&lA[seg * 512], 16, 0, 0);
            const ushort* gb = Bm + (size_t)(n0 + row) * K + k0 + scol;
            __builtin_amdgcn_global_load_lds(
                (const __attribute__((address_space(1))) void*)gb,
                (__attribute__((address_space(3))) void*)&lB[seg * 512], 16, 0, 0);
        }
        __syncthreads();   // staging complete

        short8 af[4], bf[4];
#pragma unroll
        for (int i = 0; i < 4; ++i)   // seg = wm*4+i, fragment (quad,r16) at (quad*16+r16)*8
            af[i] = *(const short8*)&lA[(wm * 4 + i) * 512 + (quad * 16 + r16) * 8];
#pragma unroll
        for (int j2 = 0; j2 < 4; ++j2)
            bf[j2] = *(const short8*)&lB[(wn * 4 + j2) * 512 + (quad * 16 + r16) * 8];
#pragma unroll
        for (int i = 0; i < 4; ++i)
#pragma unroll
            for (int j2 = 0; j2 < 4; ++j2)
                acc[i][j2] = __builtin_amdgcn_mfma_f32_16x16x32_bf16(af[i], bf[j2], acc[i][j2], 0, 0, 0);
    }

    // epilogue: C/D layout col = lane&15, row = quad*4 + reg  [m89-verified]
#pragma unroll
    for (int j2 = 0; j2 < 4; ++j2) {
        int gn = n0 + wn * 64 + j2 * 16 + r16;
        float bv = bias[gn];
        bool dorelu = gn < relu_ncols;
#pragma unroll
        for (int i = 0; i < 4; ++i) {
            int gmb = m0 + wm * 64 + i * 16 + quad * 4;
#pragma unroll
            for (int rr = 0; rr < 4; ++rr) {
                float v = acc[i][j2][rr] + bv;
                if (dorelu) v = fmaxf(v, 0.f);
                C[(size_t)(gmb + rr) * N + gn] = f2b(v);
            }
        }
    }
}

// ---------------- per-row stats over G3=[M,2304] (e | xe | ye), bf16 ----------------
// un_pot[m] = sum(e*urw)+urb ; rnx[m]=1/||xe|| ; rny[m]=1/||ye||
__global__ void row_stats_k(const ushort* __restrict__ G3, const float* __restrict__ urw,
                            const float* __restrict__ urb, float* __restrict__ un_pot,
                            float* __restrict__ rnx, float* __restrict__ rny)
{
    int m = blockIdx.x, tid = threadIdx.x;
    const ushort* row = G3 + (size_t)m * NCAT;
    float se = 0.f, sx = 0.f, sy = 0.f;
    for (int t = tid; t < DDIM; t += 256) {
        float ev = b2f(row[t]);          se += ev * urw[t];
        float xv = b2f(row[DDIM + t]);   sx += xv * xv;
        float yv = b2f(row[2*DDIM + t]); sy += yv * yv;
    }
    for (int off = 32; off; off >>= 1) {
        se += __shfl_down(se, off, 64);
        sx += __shfl_down(sx, off, 64);
        sy += __shfl_down(sy, off, 64);
    }
    __shared__ float rb[3][4];
    int lane = tid & 63, w = tid >> 6;
    if (lane == 0) { rb[0][w] = se; rb[1][w] = sx; rb[2][w] = sy; }
    __syncthreads();
    if (tid == 0) {
        float a = rb[0][0] + rb[0][1] + rb[0][2] + rb[0][3];
        float nx = sqrtf(rb[1][0] + rb[1][1] + rb[1][2] + rb[1][3]);
        float ny = sqrtf(rb[2][0] + rb[2][1] + rb[2][2] + rb[2][3]);
        un_pot[m] = a + urb[0];
        rnx[m] = 1.f / fmaxf(nx, 1e-12f);
        rny[m] = 1.f / fmaxf(ny, 1e-12f);
    }
}

// ---------------- ybar[b,d] += partial over a 64-step s chunk ----------------
__global__ void ybar_k(const ushort* __restrict__ G3, const float* __restrict__ rny,
                       float* __restrict__ ybar)
{
    int b = blockIdx.x, s0 = blockIdx.y * 64;
    int tid = threadIdx.x;
    __shared__ float sr[64];
    if (tid < 64) sr[tid] = rny[b * TSEQ + s0 + tid] * (1.0f / TSEQ);
    __syncthreads();
    float a0 = 0.f, a1 = 0.f, a2 = 0.f;
    for (int s = 0; s < 64; ++s) {
        const ushort* row = G3 + (size_t)(b * TSEQ + s0 + s) * NCAT + 2 * DDIM;
        float w = sr[s];
        a0 += b2f(row[tid])       * w;
        a1 += b2f(row[tid + 256]) * w;
        a2 += b2f(row[tid + 512]) * w;
    }
    atomicAdd(&ybar[b * DDIM + tid],       a0);
    atomicAdd(&ybar[b * DDIM + tid + 256], a1);
    atomicAdd(&ybar[b * DDIM + tid + 512], a2);
}

// ---------------- scores[m] = rw0*un_pot + rw1 * rnx[m]*dot(xe[m], ybar[b]) ----------------
__global__ void pw_scores_k(const ushort* __restrict__ G3, const float* __restrict__ ybar,
                            const float* __restrict__ rnx, const float* __restrict__ un_pot,
                            const float* __restrict__ red_w, float* __restrict__ scores)
{
    int m = blockIdx.x, tid = threadIdx.x;
    int b = m >> 10;
    const ushort* xer = G3 + (size_t)m * NCAT + DDIM;
    const float* yb = ybar + b * DDIM;
    float s = 0.f;
    for (int t = tid; t < DDIM; t += 256) s += b2f(xer[t]) * yb[t];
    for (int off = 32; off; off >>= 1) s += __shfl_down(s, off, 64);
    __shared__ float rb[4];
    int lane = tid & 63, w = tid >> 6;
    if (lane == 0) rb[w] = s;
    __syncthreads();
    if (tid == 0) {
        float dot = rb[0] + rb[1] + rb[2] + rb[3];
        scores[m] = red_w[0] * un_pot[m] + red_w[1] * (rnx[m] * dot);
    }
}

// ---------------- softmax over T per batch ----------------
__global__ void softmax_k(const float* __restrict__ scores, float* __restrict__ wsm)
{
    int b = blockIdx.x, tid = threadIdx.x;
    float v[4];
    float lm = -1e30f;
#pragma unroll
    for (int i = 0; i < 4; ++i) {
        v[i] = scores[b * TSEQ + i * 256 + tid];
        lm = fmaxf(lm, v[i]);
    }
    for (int off = 32; off; off >>= 1) lm = fmaxf(lm, __shfl_down(lm, off, 64));
    __shared__ float rb[4];
    __shared__ float smax, ssum;
    int lane = tid & 63, w = tid >> 6;
    if (lane == 0) rb[w] = lm;
    __syncthreads();
    if (tid == 0) smax = fmaxf(fmaxf(rb[0], rb[1]), fmaxf(rb[2], rb[3]));
    __syncthreads();
    float e[4];
    float ls = 0.f;
#pragma unroll
    for (int i = 0; i < 4; ++i) { e[i] = expf(v[i] - smax); ls += e[i]; }
    for (int off = 32; off; off >>= 1) ls += __shfl_down(ls, off, 64);
    __syncthreads();
    if (lane == 0) rb[w] = ls;
    __syncthreads();
    if (tid == 0) ssum = rb[0] + rb[1] + rb[2] + rb[3];
    __syncthreads();
    float inv = 1.f / ssum;
#pragma unroll
    for (int i = 0; i < 4; ++i) wsm[b * TSEQ + i * 256 + tid] = e[i] * inv;
}

// ---------------- out[b,d] += partial over a 64-step t chunk ----------------
__global__ void out_k(const ushort* __restrict__ U16, const float* __restrict__ wsm,
                      float* __restrict__ out)
{
    int b = blockIdx.x, t0 = blockIdx.y * 64;
    int tid = threadIdx.x;
    __shared__ float sw[64];
    if (tid < 64) sw[tid] = wsm[b * TSEQ + t0 + tid];
    __syncthreads();
    float a0 = 0.f, a1 = 0.f, a2 = 0.f;
    for (int t = 0; t < 64; ++t) {
        const ushort* row = U16 + (size_t)(b * TSEQ + t0 + t) * DDIM;
        float w = sw[t];
        a0 += b2f(row[tid])       * w;
        a1 += b2f(row[tid + 256]) * w;
        a2 += b2f(row[tid + 512]) * w;
    }
    atomicAdd(&out[b * DDIM + tid],       a0);
    atomicAdd(&out[b * DDIM + tid + 256], a1);
    atomicAdd(&out[b * DDIM + tid + 512], a2);
}

// ---------------- workspace layout (bytes) ----------------
// G3 (e|xe|ye bf16, 151 MB) aliases the X16+H16 region (dead after GEMM2).
static const size_t O_X16   = 0;            // 32768*1536*2 = 100663296
static const size_t O_H16   = 100663296;    // 100663296
static const size_t O_G3    = 0;            // 150994944 (alias)
static const size_t O_U16   = 201326592;    // 50331648
static const size_t O_W1    = 251658240;    // 4718592
static const size_t O_W2    = 256376832;    // 2359296
static const size_t O_W3    = 258736128;    // 3538944
static const size_t O_B3    = 262275072;    // 9216
static const size_t O_UNPOT = 262284288;    // 131072
static const size_t O_RNX   = 262415360;    // 131072
static const size_t O_RNY   = 262546432;    // 131072
static const size_t O_SCORE = 262677504;    // 131072
static const size_t O_WSM   = 262808576;    // 131072
static const size_t O_YBAR  = 262939648;    // 98304
// total: 263037952 bytes (~263 MB)

extern "C" void kernel_launch(void* const* d_in, const int* in_sizes, int n_in,
                              void* d_out, int out_size, void* d_ws, size_t ws_size,
                              hipStream_t stream)
{
    const float* x        = (const float*)d_in[0];
    const float* fc1_w    = (const float*)d_in[1];
    const float* fc1_b    = (const float*)d_in[2];
    const float* fc2_w    = (const float*)d_in[3];
    const float* fc2_b    = (const float*)d_in[4];
    const float* un_emb_w = (const float*)d_in[5];
    const float* un_emb_b = (const float*)d_in[6];
    const float* un_red_w = (const float*)d_in[7];
    const float* un_red_b = (const float*)d_in[8];
    const float* pw_x_w   = (const float*)d_in[9];
    const float* pw_x_b   = (const float*)d_in[10];
    const float* pw_y_w   = (const float*)d_in[11];
    const float* pw_y_b   = (const float*)d_in[12];
    const float* red_w    = (const float*)d_in[13];

    char* ws = (char*)d_ws;
    ushort* X16 = (ushort*)(ws + O_X16);
    ushort* H16 = (ushort*)(ws + O_H16);
    ushort* G3  = (ushort*)(ws + O_G3);
    ushort* U16 = (ushort*)(ws + O_U16);
    ushort* W1  = (ushort*)(ws + O_W1);
    ushort* W2  = (ushort*)(ws + O_W2);
    ushort* W3  = (ushort*)(ws + O_W3);
    float*  B3  = (float*)(ws + O_B3);
    float*  UNPOT = (float*)(ws + O_UNPOT);
    float*  RNX = (float*)(ws + O_RNX);
    float*  RNY = (float*)(ws + O_RNY);
    float*  SCORES = (float*)(ws + O_SCORE);
    float*  WSM = (float*)(ws + O_WSM);
    float*  YBAR = (float*)(ws + O_YBAR);

    // --- zero the atomic accumulators (ws/d_out are poisoned 0xAA each call) ---
    hipMemsetAsync(YBAR, 0, BBATCH * DDIM * sizeof(float), stream);
    hipMemsetAsync(d_out, 0, BBATCH * DDIM * sizeof(float), stream);

    // --- convert inputs to bf16 ---
    cvt_bf16<<<49152, 256, 0, stream>>>(x, X16, 12582912);   // 32768*1536/4
    cvt_weights<<<5187, 256, 0, stream>>>(fc1_w, fc2_w, un_emb_w, pw_x_w, pw_y_w,
                                          un_emb_b, pw_x_b, pw_y_b, W1, W2, W3, B3);

    // --- GEMM chain (1-D grid, XCD-pinned swizzle inside kernel) ---
    // h = relu(x @ fc1_w^T + fc1_b)            [M,1536]
    gemm_bt<<<(MROWS / 128) * (INDIM / 128), 256, 0, stream>>>(
        X16, W1, fc1_b, H16, MROWS, INDIM, INDIM, INDIM);
    // u = h @ fc2_w^T + fc2_b                  [M,768]
    gemm_bt<<<(MROWS / 128) * (DDIM / 128), 256, 0, stream>>>(
        H16, W2, fc2_b, U16, MROWS, DDIM, INDIM, 0);
    // [e|xe|ye] = u @ [un_emb|pw_x|pw_y]^T + b  [M,2304], relu on first 768 cols (e)
    gemm_bt<<<(MROWS / 128) * (NCAT / 128), 256, 0, stream>>>(
        U16, W3, B3, G3, MROWS, NCAT, DDIM, DDIM);

    // --- reductions / attention ---
    row_stats_k<<<MROWS, 256, 0, stream>>>(G3, un_red_w, un_red_b, UNPOT, RNX, RNY);
    ybar_k<<<dim3(BBATCH, 16), 256, 0, stream>>>(G3, RNY, YBAR);
    pw_scores_k<<<MROWS, 256, 0, stream>>>(G3, YBAR, RNX, UNPOT, red_w, SCORES);
    softmax_k<<<BBATCH, 256, 0, stream>>>(SCORES, WSM);
    out_k<<<dim3(BBATCH, 16), 256, 0, stream>>>(U16, WSM, (float*)d_out);
}

// Round 4
// 842.022 us; speedup vs baseline: 1.2395x; 1.2239x over previous
//
#include <hip/hip_runtime.h>
#include <stdint.h>

// Problem dims
#define MROWS 32768   // B*T
#define TSEQ  1024
#define BBATCH 32
#define INDIM 1536
#define DDIM  768
#define NCAT  2304    // un_emb (768) + pw_x (768) + pw_y (768)

typedef short short8 __attribute__((ext_vector_type(8)));
typedef float f32x4  __attribute__((ext_vector_type(4)));

__device__ __forceinline__ float b2f(ushort u) {
    union { uint32_t u; float f; } x; x.u = ((uint32_t)u) << 16; return x.f;
}
__device__ __forceinline__ ushort f2b(float f) {
    union { float f; uint32_t u; } x; x.f = f;
    uint32_t r = x.u + 0x7fffu + ((x.u >> 16) & 1u);
    return (ushort)(r >> 16);
}

// ---------------- fp32 -> bf16 conversion (vectorized x4) ----------------
__global__ void cvt_bf16(const float* __restrict__ in, ushort* __restrict__ out, int n4) {
    int i = blockIdx.x * blockDim.x + threadIdx.x;
    if (i < n4) {
        float4 v = ((const float4*)in)[i];
        ushort4 o;
        o.x = f2b(v.x); o.y = f2b(v.y); o.z = f2b(v.z); o.w = f2b(v.w);
        ((ushort4*)out)[i] = o;
    }
}

__device__ __forceinline__ void cvt4(const float* __restrict__ in, ushort* __restrict__ out, int i) {
    float4 v = ((const float4*)in)[i];
    ushort4 o;
    o.x = f2b(v.x); o.y = f2b(v.y); o.z = f2b(v.z); o.w = f2b(v.w);
    ((ushort4*)out)[i] = o;
}

// All small weight conversions + bias concat in ONE launch.
__global__ void cvt_weights(const float* __restrict__ fc1_w, const float* __restrict__ fc2_w,
                            const float* __restrict__ w3a, const float* __restrict__ w3b,
                            const float* __restrict__ w3c,
                            const float* __restrict__ ba, const float* __restrict__ bb,
                            const float* __restrict__ bc,
                            ushort* __restrict__ W1, ushort* __restrict__ W2,
                            ushort* __restrict__ W3, float* __restrict__ B3)
{
    int i = blockIdx.x * 256 + threadIdx.x;  // float4 index
    if (i < 589824)        cvt4(fc1_w, W1, i);
    else if (i < 884736)   cvt4(fc2_w, W2, i - 589824);
    else if (i < 1032192)  cvt4(w3a,  W3,           i - 884736);
    else if (i < 1179648)  cvt4(w3b,  W3 + 589824,  i - 1032192);
    else if (i < 1327104)  cvt4(w3c,  W3 + 1179648, i - 1179648);
    else if (i < 1327680) {
        int j = i - 1327104;  // 0..575 float4s of B3 (2304 floats)
        const float* src = (j < 192) ? ba : (j < 384) ? bb : bc;
        int off = (j < 192) ? j : (j < 384) ? (j - 192) : (j - 384);
        ((float4*)B3)[j] = ((const float4*)src)[off];
    }
}

// ---------------- bf16 GEMM: C[M,N] = A[M,K] * B[N,K]^T + bias, optional relu on cols < relu_ncols
// 128x128 tile / block, 4 waves (2x2), each wave 64x64 = 4x4 MFMA 16x16x32 subtiles.
//
// Staging (global_load_lds width=16, LDS dest = base + lane*16B fixed):
//   lane s -> global (row = s>>2, kb = (s&3) ^ ((s>>3)&3)) of its 16x32 segment.
//   * 4 consecutive lanes cover one row's full 64 B (XOR only permutes the four
//     16B granules within the row) -> coalesced like round-1.
//   * Fragment read granule for lane l (r=l&15, q=l>>4): G = 4r + (q ^ ((r>>1)&3));
//     any 8 consecutive read lanes hit G mod 8 = {0,4,1,5,2,6,3,7} -> conflict-free.
//   This combines R1's coalescing (229us) with R3's zero conflicts.
//
// XCD-pinned swizzle: all ntiles consumers of one A-tile consecutive on ONE XCD
// (A-tile L2-resident; R2 showed cross-XCD reuse costs ~85us on GEMM1).
// Requires (M/128)%8==0, N%128==0, K%32==0.
__global__ __launch_bounds__(256, 2)
void gemm_bt(const ushort* __restrict__ A, const ushort* __restrict__ Bm,
             const float* __restrict__ bias, ushort* __restrict__ C,
             int M, int N, int K, int relu_ncols)
{
    __shared__ __align__(16) ushort lA[128 * 32];  // 8 KB, 8 segments of 16x32
    __shared__ __align__(16) ushort lB[128 * 32];  // 8 KB

    const int tid  = threadIdx.x;
    const int lane = tid & 63, wave = tid >> 6;
    const int wm = wave & 1, wn = wave >> 1;       // 2x2 wave grid
    const int quad = lane >> 4, r16 = lane & 15;

    // XCD-pinned block swizzle
    const int ntiles = N >> 7;
    const int xcd = blockIdx.x & 7;
    const int j   = blockIdx.x >> 3;
    const int g   = j / ntiles;            // m-group within this XCD
    const int n_t = j - g * ntiles;
    const int m_t = xcd + (g << 3);
    const int m0 = m_t * 128, n0 = n_t * 128;

    // staging lane->global map (see header comment)
    const int srow = lane >> 2;
    const int scol = ((lane & 3) ^ ((lane >> 3) & 3)) * 8;
    // fragment-read granule offset (ushorts): (r*4 + (q ^ ((r>>1)&3))) * 8
    const int goff = (r16 << 5) + ((quad ^ ((r16 >> 1) & 3)) << 3);

    f32x4 acc[4][4] = {};

    const int kIters = K >> 5;
    for (int kt = 0; kt < kIters; ++kt) {
        const int k0 = kt << 5;
        __syncthreads();   // previous iteration's LDS reads complete
#pragma unroll
        for (int c = 0; c < 2; ++c) {
            int seg = wave * 2 + c;
            int row = seg * 16 + srow;
            const ushort* ga = A + (size_t)(m0 + row) * K + k0 + scol;
            __builtin_amdgcn_global_load_lds(
                (const __attribute__((address_space(1))) void*)ga,
                (__attribute__((address_space(3))) void*)&lA[seg * 512], 16, 0, 0);
            const ushort* gb = Bm + (size_t)(n0 + row) * K + k0 + scol;
            __builtin_amdgcn_global_load_lds(
                (const __attribute__((address_space(1))) void*)gb,
                (__attribute__((address_space(3))) void*)&lB[seg * 512], 16, 0, 0);
        }
        __syncthreads();   // staging complete

        short8 af[4], bf[4];
#pragma unroll
        for (int i = 0; i < 4; ++i)
            af[i] = *(const short8*)&lA[(wm * 4 + i) * 512 + goff];
#pragma unroll
        for (int j2 = 0; j2 < 4; ++j2)
            bf[j2] = *(const short8*)&lB[(wn * 4 + j2) * 512 + goff];
#pragma unroll
        for (int i = 0; i < 4; ++i)
#pragma unroll
            for (int j2 = 0; j2 < 4; ++j2)
                acc[i][j2] = __builtin_amdgcn_mfma_f32_16x16x32_bf16(af[i], bf[j2], acc[i][j2], 0, 0, 0);
    }

    // epilogue: C/D layout col = lane&15, row = quad*4 + reg  [m89-verified]
#pragma unroll
    for (int j2 = 0; j2 < 4; ++j2) {
        int gn = n0 + wn * 64 + j2 * 16 + r16;
        float bv = bias[gn];
        bool dorelu = gn < relu_ncols;
#pragma unroll
        for (int i = 0; i < 4; ++i) {
            int gmb = m0 + wm * 64 + i * 16 + quad * 4;
#pragma unroll
            for (int rr = 0; rr < 4; ++rr) {
                float v = acc[i][j2][rr] + bv;
                if (dorelu) v = fmaxf(v, 0.f);
                C[(size_t)(gmb + rr) * N + gn] = f2b(v);
            }
        }
    }
}

// ---------------- per-row stats over G3=[M,2304] (e | xe | ye), bf16 ----------------
// un_pot[m] = sum(e*urw)+urb ; rnx[m]=1/||xe|| ; rny[m]=1/||ye||
__global__ void row_stats_k(const ushort* __restrict__ G3, const float* __restrict__ urw,
                            const float* __restrict__ urb, float* __restrict__ un_pot,
                            float* __restrict__ rnx, float* __restrict__ rny)
{
    int m = blockIdx.x, tid = threadIdx.x;
    const ushort* row = G3 + (size_t)m * NCAT;
    float se = 0.f, sx = 0.f, sy = 0.f;
    for (int t = tid; t < DDIM; t += 256) {
        float ev = b2f(row[t]);          se += ev * urw[t];
        float xv = b2f(row[DDIM + t]);   sx += xv * xv;
        float yv = b2f(row[2*DDIM + t]); sy += yv * yv;
    }
    for (int off = 32; off; off >>= 1) {
        se += __shfl_down(se, off, 64);
        sx += __shfl_down(sx, off, 64);
        sy += __shfl_down(sy, off, 64);
    }
    __shared__ float rb[3][4];
    int lane = tid & 63, w = tid >> 6;
    if (lane == 0) { rb[0][w] = se; rb[1][w] = sx; rb[2][w] = sy; }
    __syncthreads();
    if (tid == 0) {
        float a = rb[0][0] + rb[0][1] + rb[0][2] + rb[0][3];
        float nx = sqrtf(rb[1][0] + rb[1][1] + rb[1][2] + rb[1][3]);
        float ny = sqrtf(rb[2][0] + rb[2][1] + rb[2][2] + rb[2][3]);
        un_pot[m] = a + urb[0];
        rnx[m] = 1.f / fmaxf(nx, 1e-12f);
        rny[m] = 1.f / fmaxf(ny, 1e-12f);
    }
}

// ---------------- ybar[b,d] += partial over a 64-step s chunk ----------------
__global__ void ybar_k(const ushort* __restrict__ G3, const float* __restrict__ rny,
                       float* __restrict__ ybar)
{
    int b = blockIdx.x, s0 = blockIdx.y * 64;
    int tid = threadIdx.x;
    __shared__ float sr[64];
    if (tid < 64) sr[tid] = rny[b * TSEQ + s0 + tid] * (1.0f / TSEQ);
    __syncthreads();
    float a0 = 0.f, a1 = 0.f, a2 = 0.f;
    for (int s = 0; s < 64; ++s) {
        const ushort* row = G3 + (size_t)(b * TSEQ + s0 + s) * NCAT + 2 * DDIM;
        float w = sr[s];
        a0 += b2f(row[tid])       * w;
        a1 += b2f(row[tid + 256]) * w;
        a2 += b2f(row[tid + 512]) * w;
    }
    atomicAdd(&ybar[b * DDIM + tid],       a0);
    atomicAdd(&ybar[b * DDIM + tid + 256], a1);
    atomicAdd(&ybar[b * DDIM + tid + 512], a2);
}

// ---------------- scores[m] = rw0*un_pot + rw1 * rnx[m]*dot(xe[m], ybar[b]) ----------------
__global__ void pw_scores_k(const ushort* __restrict__ G3, const float* __restrict__ ybar,
                            const float* __restrict__ rnx, const float* __restrict__ un_pot,
                            const float* __restrict__ red_w, float* __restrict__ scores)
{
    int m = blockIdx.x, tid = threadIdx.x;
    int b = m >> 10;
    const ushort* xer = G3 + (size_t)m * NCAT + DDIM;
    const float* yb = ybar + b * DDIM;
    float s = 0.f;
    for (int t = tid; t < DDIM; t += 256) s += b2f(xer[t]) * yb[t];
    for (int off = 32; off; off >>= 1) s += __shfl_down(s, off, 64);
    __shared__ float rb[4];
    int lane = tid & 63, w = tid >> 6;
    if (lane == 0) rb[w] = s;
    __syncthreads();
    if (tid == 0) {
        float dot = rb[0] + rb[1] + rb[2] + rb[3];
        scores[m] = red_w[0] * un_pot[m] + red_w[1] * (rnx[m] * dot);
    }
}

// ---------------- softmax over T per batch ----------------
__global__ void softmax_k(const float* __restrict__ scores, float* __restrict__ wsm)
{
    int b = blockIdx.x, tid = threadIdx.x;
    float v[4];
    float lm = -1e30f;
#pragma unroll
    for (int i = 0; i < 4; ++i) {
        v[i] = scores[b * TSEQ + i * 256 + tid];
        lm = fmaxf(lm, v[i]);
    }
    for (int off = 32; off; off >>= 1) lm = fmaxf(lm, __shfl_down(lm, off, 64));
    __shared__ float rb[4];
    __shared__ float smax, ssum;
    int lane = tid & 63, w = tid >> 6;
    if (lane == 0) rb[w] = lm;
    __syncthreads();
    if (tid == 0) smax = fmaxf(fmaxf(rb[0], rb[1]), fmaxf(rb[2], rb[3]));
    __syncthreads();
    float e[4];
    float ls = 0.f;
#pragma unroll
    for (int i = 0; i < 4; ++i) { e[i] = expf(v[i] - smax); ls += e[i]; }
    for (int off = 32; off; off >>= 1) ls += __shfl_down(ls, off, 64);
    __syncthreads();
    if (lane == 0) rb[w] = ls;
    __syncthreads();
    if (tid == 0) ssum = rb[0] + rb[1] + rb[2] + rb[3];
    __syncthreads();
    float inv = 1.f / ssum;
#pragma unroll
    for (int i = 0; i < 4; ++i) wsm[b * TSEQ + i * 256 + tid] = e[i] * inv;
}

// ---------------- out[b,d] += partial over a 64-step t chunk ----------------
__global__ void out_k(const ushort* __restrict__ U16, const float* __restrict__ wsm,
                      float* __restrict__ out)
{
    int b = blockIdx.x, t0 = blockIdx.y * 64;
    int tid = threadIdx.x;
    __shared__ float sw[64];
    if (tid < 64) sw[tid] = wsm[b * TSEQ + t0 + tid];
    __syncthreads();
    float a0 = 0.f, a1 = 0.f, a2 = 0.f;
    for (int t = 0; t < 64; ++t) {
        const ushort* row = U16 + (size_t)(b * TSEQ + t0 + t) * DDIM;
        float w = sw[t];
        a0 += b2f(row[tid])       * w;
        a1 += b2f(row[tid + 256]) * w;
        a2 += b2f(row[tid + 512]) * w;
    }
    atomicAdd(&out[b * DDIM + tid],       a0);
    atomicAdd(&out[b * DDIM + tid + 256], a1);
    atomicAdd(&out[b * DDIM + tid + 512], a2);
}

// ---------------- workspace layout (bytes) ----------------
// G3 (e|xe|ye bf16, 151 MB) aliases the X16+H16 region (dead after GEMM2).
static const size_t O_X16   = 0;            // 32768*1536*2 = 100663296
static const size_t O_H16   = 100663296;    // 100663296
static const size_t O_G3    = 0;            // 150994944 (alias)
static const size_t O_U16   = 201326592;    // 50331648
static const size_t O_W1    = 251658240;    // 4718592
static const size_t O_W2    = 256376832;    // 2359296
static const size_t O_W3    = 258736128;    // 3538944
static const size_t O_B3    = 262275072;    // 9216
static const size_t O_UNPOT = 262284288;    // 131072
static const size_t O_RNX   = 262415360;    // 131072
static const size_t O_RNY   = 262546432;    // 131072
static const size_t O_SCORE = 262677504;    // 131072
static const size_t O_WSM   = 262808576;    // 131072
static const size_t O_YBAR  = 262939648;    // 98304
// total: 263037952 bytes (~263 MB)

extern "C" void kernel_launch(void* const* d_in, const int* in_sizes, int n_in,
                              void* d_out, int out_size, void* d_ws, size_t ws_size,
                              hipStream_t stream)
{
    const float* x        = (const float*)d_in[0];
    const float* fc1_w    = (const float*)d_in[1];
    const float* fc1_b    = (const float*)d_in[2];
    const float* fc2_w    = (const float*)d_in[3];
    const float* fc2_b    = (const float*)d_in[4];
    const float* un_emb_w = (const float*)d_in[5];
    const float* un_emb_b = (const float*)d_in[6];
    const float* un_red_w = (const float*)d_in[7];
    const float* un_red_b = (const float*)d_in[8];
    const float* pw_x_w   = (const float*)d_in[9];
    const float* pw_x_b   = (const float*)d_in[10];
    const float* pw_y_w   = (const float*)d_in[11];
    const float* pw_y_b   = (const float*)d_in[12];
    const float* red_w    = (const float*)d_in[13];

    char* ws = (char*)d_ws;
    ushort* X16 = (ushort*)(ws + O_X16);
    ushort* H16 = (ushort*)(ws + O_H16);
    ushort* G3  = (ushort*)(ws + O_G3);
    ushort* U16 = (ushort*)(ws + O_U16);
    ushort* W1  = (ushort*)(ws + O_W1);
    ushort* W2  = (ushort*)(ws + O_W2);
    ushort* W3  = (ushort*)(ws + O_W3);
    float*  B3  = (float*)(ws + O_B3);
    float*  UNPOT = (float*)(ws + O_UNPOT);
    float*  RNX = (float*)(ws + O_RNX);
    float*  RNY = (float*)(ws + O_RNY);
    float*  SCORES = (float*)(ws + O_SCORE);
    float*  WSM = (float*)(ws + O_WSM);
    float*  YBAR = (float*)(ws + O_YBAR);

    // --- zero the atomic accumulators (ws/d_out are poisoned 0xAA each call) ---
    hipMemsetAsync(YBAR, 0, BBATCH * DDIM * sizeof(float), stream);
    hipMemsetAsync(d_out, 0, BBATCH * DDIM * sizeof(float), stream);

    // --- convert inputs to bf16 ---
    cvt_bf16<<<49152, 256, 0, stream>>>(x, X16, 12582912);   // 32768*1536/4
    cvt_weights<<<5187, 256, 0, stream>>>(fc1_w, fc2_w, un_emb_w, pw_x_w, pw_y_w,
                                          un_emb_b, pw_x_b, pw_y_b, W1, W2, W3, B3);

    // --- GEMM chain (1-D grid, XCD-pinned swizzle inside kernel) ---
    // h = relu(x @ fc1_w^T + fc1_b)            [M,1536]
    gemm_bt<<<(MROWS / 128) * (INDIM / 128), 256, 0, stream>>>(
        X16, W1, fc1_b, H16, MROWS, INDIM, INDIM, INDIM);
    // u = h @ fc2_w^T + fc2_b                  [M,768]
    gemm_bt<<<(MROWS / 128) * (DDIM / 128), 256, 0, stream>>>(
        H16, W2, fc2_b, U16, MROWS, DDIM, INDIM, 0);
    // [e|xe|ye] = u @ [un_emb|pw_x|pw_y]^T + b  [M,2304], relu on first 768 cols (e)
    gemm_bt<<<(MROWS / 128) * (NCAT / 128), 256, 0, stream>>>(
        U16, W3, B3, G3, MROWS, NCAT, DDIM, DDIM);

    // --- reductions / attention ---
    row_stats_k<<<MROWS, 256, 0, stream>>>(G3, un_red_w, un_red_b, UNPOT, RNX, RNY);
    ybar_k<<<dim3(BBATCH, 16), 256, 0, stream>>>(G3, RNY, YBAR);
    pw_scores_k<<<MROWS, 256, 0, stream>>>(G3, YBAR, RNX, UNPOT, red_w, SCORES);
    softmax_k<<<BBATCH, 256, 0, stream>>>(SCORES, WSM);
    out_k<<<dim3(BBATCH, 16), 256, 0, stream>>>(U16, WSM, (float*)d_out);
}

// Round 5
// 755.532 us; speedup vs baseline: 1.3814x; 1.1145x over previous
//
#include <hip/hip_runtime.h>
#include <stdint.h>

// Problem dims
#define MROWS 32768   // B*T
#define TSEQ  1024
#define BBATCH 32
#define INDIM 1536
#define DDIM  768
#define NCAT  2304    // un_emb (768) + pw_x (768) + pw_y (768)

typedef short short8 __attribute__((ext_vector_type(8)));
typedef float f32x4  __attribute__((ext_vector_type(4)));

__device__ __forceinline__ float b2f(ushort u) {
    union { uint32_t u; float f; } x; x.u = ((uint32_t)u) << 16; return x.f;
}
__device__ __forceinline__ ushort f2b(float f) {
    union { float f; uint32_t u; } x; x.f = f;
    uint32_t r = x.u + 0x7fffu + ((x.u >> 16) & 1u);
    return (ushort)(r >> 16);
}

// ---------------- fp32 -> bf16 conversion (vectorized x4) ----------------
__global__ void cvt_bf16(const float* __restrict__ in, ushort* __restrict__ out, int n4) {
    int i = blockIdx.x * blockDim.x + threadIdx.x;
    if (i < n4) {
        float4 v = ((const float4*)in)[i];
        ushort4 o;
        o.x = f2b(v.x); o.y = f2b(v.y); o.z = f2b(v.z); o.w = f2b(v.w);
        ((ushort4*)out)[i] = o;
    }
}

__device__ __forceinline__ void cvt4(const float* __restrict__ in, ushort* __restrict__ out, int i) {
    float4 v = ((const float4*)in)[i];
    ushort4 o;
    o.x = f2b(v.x); o.y = f2b(v.y); o.z = f2b(v.z); o.w = f2b(v.w);
    ((ushort4*)out)[i] = o;
}

// All small weight conversions + bias concat in ONE launch.
__global__ void cvt_weights(const float* __restrict__ fc1_w, const float* __restrict__ fc2_w,
                            const float* __restrict__ w3a, const float* __restrict__ w3b,
                            const float* __restrict__ w3c,
                            const float* __restrict__ ba, const float* __restrict__ bb,
                            const float* __restrict__ bc,
                            ushort* __restrict__ W1, ushort* __restrict__ W2,
                            ushort* __restrict__ W3, float* __restrict__ B3)
{
    int i = blockIdx.x * 256 + threadIdx.x;  // float4 index
    if (i < 589824)        cvt4(fc1_w, W1, i);
    else if (i < 884736)   cvt4(fc2_w, W2, i - 589824);
    else if (i < 1032192)  cvt4(w3a,  W3,           i - 884736);
    else if (i < 1179648)  cvt4(w3b,  W3 + 589824,  i - 1032192);
    else if (i < 1327104)  cvt4(w3c,  W3 + 1179648, i - 1179648);
    else if (i < 1327680) {
        int j = i - 1327104;  // 0..575 float4s of B3 (2304 floats)
        const float* src = (j < 192) ? ba : (j < 384) ? bb : bc;
        int off = (j < 192) ? j : (j < 384) ? (j - 192) : (j - 384);
        ((float4*)B3)[j] = ((const float4*)src)[off];
    }
}

// ---------------- bf16 GEMM: C[M,N] = A[M,K] * B[N,K]^T + bias, optional relu on cols < relu_ncols
// 128x128 tile / block, 4 waves (2x2), each wave 64x64 = 4x4 MFMA 16x16x32 subtiles.
// BK=64: each staging round loads a 128x64 tile of A and B (two 32-k halves),
// so each barrier pair covers 32 MFMAs/wave instead of 16 — halves the
// vmcnt(0)+s_barrier drain events (the ~20% structural stall, m98). LDS 32 KB
// keeps occupancy AGPR-bound (~4 blocks/CU), unlike BK=128's 64 KB (m132 regression).
//
// Staging (global_load_lds width=16, LDS dest = base + lane*16B fixed), per
// 16-row x 32-k segment (512 ushorts = one wave-instruction):
//   lane s -> global (row = s>>2, kb = (s&3) ^ ((s>>3)&3)) of its segment.
//   * 4 consecutive lanes cover one row's full 64 B -> coalesced (R1 property).
//   * Fragment read granule for lane l (r=l&15, q=l>>4): G = 4r + (q ^ ((r>>1)&3));
//     any 8 consecutive read lanes hit G mod 8 = {0,4,1,5,2,6,3,7} -> conflict-free
//     (R4 measured: SQ_LDS_BANK_CONFLICT = 0).
//
// XCD-pinned swizzle: all ntiles consumers of one A-tile consecutive on ONE XCD
// (A-tile L2-resident; R2 showed cross-XCD reuse costs ~85us on GEMM1).
// Requires (M/128)%8==0, N%128==0, K%64==0.
__global__ __launch_bounds__(256, 2)
void gemm_bt(const ushort* __restrict__ A, const ushort* __restrict__ Bm,
             const float* __restrict__ bias, ushort* __restrict__ C,
             int M, int N, int K, int relu_ncols)
{
    __shared__ __align__(16) ushort lA[128 * 64];  // 16 KB, 16 segments of 16x32
    __shared__ __align__(16) ushort lB[128 * 64];  // 16 KB

    const int tid  = threadIdx.x;
    const int lane = tid & 63, wave = tid >> 6;
    const int wm = wave & 1, wn = wave >> 1;       // 2x2 wave grid
    const int quad = lane >> 4, r16 = lane & 15;

    // XCD-pinned block swizzle
    const int ntiles = N >> 7;
    const int xcd = blockIdx.x & 7;
    const int j   = blockIdx.x >> 3;
    const int g   = j / ntiles;            // m-group within this XCD
    const int n_t = j - g * ntiles;
    const int m_t = xcd + (g << 3);
    const int m0 = m_t * 128, n0 = n_t * 128;

    // staging lane->global map (see header comment)
    const int srow = lane >> 2;
    const int scol = ((lane & 3) ^ ((lane >> 3) & 3)) * 8;
    // fragment-read granule offset (ushorts): (r*4 + (q ^ ((r>>1)&3))) * 8
    const int goff = (r16 << 5) + ((quad ^ ((r16 >> 1) & 3)) << 3);

    f32x4 acc[4][4] = {};

    const int kIters = K >> 6;
    for (int kt = 0; kt < kIters; ++kt) {
        const int k0 = kt << 6;
        __syncthreads();   // previous round's LDS reads complete
        // 16 segments per matrix: seg S = kh*8 + rs; this wave stages S = wave*4+c.
#pragma unroll
        for (int c = 0; c < 4; ++c) {
            int S  = wave * 4 + c;
            int kh = S >> 3, rs = S & 7;
            int row = rs * 16 + srow;
            int kc  = k0 + kh * 32 + scol;
            const ushort* ga = A + (size_t)(m0 + row) * K + kc;
            __builtin_amdgcn_global_load_lds(
                (const __attribute__((address_space(1))) void*)ga,
                (__attribute__((address_space(3))) void*)&lA[S * 512], 16, 0, 0);
            const ushort* gb = Bm + (size_t)(n0 + row) * K + kc;
            __builtin_amdgcn_global_load_lds(
                (const __attribute__((address_space(1))) void*)gb,
                (__attribute__((address_space(3))) void*)&lB[S * 512], 16, 0, 0);
        }
        __syncthreads();   // staging complete

#pragma unroll
        for (int kh = 0; kh < 2; ++kh) {
            short8 af[4], bf[4];
#pragma unroll
            for (int i = 0; i < 4; ++i)
                af[i] = *(const short8*)&lA[kh * 4096 + (wm * 4 + i) * 512 + goff];
#pragma unroll
            for (int j2 = 0; j2 < 4; ++j2)
                bf[j2] = *(const short8*)&lB[kh * 4096 + (wn * 4 + j2) * 512 + goff];
#pragma unroll
            for (int i = 0; i < 4; ++i)
#pragma unroll
                for (int j2 = 0; j2 < 4; ++j2)
                    acc[i][j2] = __builtin_amdgcn_mfma_f32_16x16x32_bf16(af[i], bf[j2], acc[i][j2], 0, 0, 0);
        }
    }

    // epilogue: C/D layout col = lane&15, row = quad*4 + reg  [m89-verified]
#pragma unroll
    for (int j2 = 0; j2 < 4; ++j2) {
        int gn = n0 + wn * 64 + j2 * 16 + r16;
        float bv = bias[gn];
        bool dorelu = gn < relu_ncols;
#pragma unroll
        for (int i = 0; i < 4; ++i) {
            int gmb = m0 + wm * 64 + i * 16 + quad * 4;
#pragma unroll
            for (int rr = 0; rr < 4; ++rr) {
                float v = acc[i][j2][rr] + bv;
                if (dorelu) v = fmaxf(v, 0.f);
                C[(size_t)(gmb + rr) * N + gn] = f2b(v);
            }
        }
    }
}

// ---------------- per-row stats over G3=[M,2304] (e | xe | ye), bf16 ----------------
// un_pot[m] = sum(e*urw)+urb ; rnx[m]=1/||xe|| ; rny[m]=1/||ye||
__global__ void row_stats_k(const ushort* __restrict__ G3, const float* __restrict__ urw,
                            const float* __restrict__ urb, float* __restrict__ un_pot,
                            float* __restrict__ rnx, float* __restrict__ rny)
{
    int m = blockIdx.x, tid = threadIdx.x;
    const ushort* row = G3 + (size_t)m * NCAT;
    float se = 0.f, sx = 0.f, sy = 0.f;
    for (int t = tid; t < DDIM; t += 256) {
        float ev = b2f(row[t]);          se += ev * urw[t];
        float xv = b2f(row[DDIM + t]);   sx += xv * xv;
        float yv = b2f(row[2*DDIM + t]); sy += yv * yv;
    }
    for (int off = 32; off; off >>= 1) {
        se += __shfl_down(se, off, 64);
        sx += __shfl_down(sx, off, 64);
        sy += __shfl_down(sy, off, 64);
    }
    __shared__ float rb[3][4];
    int lane = tid & 63, w = tid >> 6;
    if (lane == 0) { rb[0][w] = se; rb[1][w] = sx; rb[2][w] = sy; }
    __syncthreads();
    if (tid == 0) {
        float a = rb[0][0] + rb[0][1] + rb[0][2] + rb[0][3];
        float nx = sqrtf(rb[1][0] + rb[1][1] + rb[1][2] + rb[1][3]);
        float ny = sqrtf(rb[2][0] + rb[2][1] + rb[2][2] + rb[2][3]);
        un_pot[m] = a + urb[0];
        rnx[m] = 1.f / fmaxf(nx, 1e-12f);
        rny[m] = 1.f / fmaxf(ny, 1e-12f);
    }
}

// ---------------- ybar[b,d] += partial over a 64-step s chunk ----------------
__global__ void ybar_k(const ushort* __restrict__ G3, const float* __restrict__ rny,
                       float* __restrict__ ybar)
{
    int b = blockIdx.x, s0 = blockIdx.y * 64;
    int tid = threadIdx.x;
    __shared__ float sr[64];
    if (tid < 64) sr[tid] = rny[b * TSEQ + s0 + tid] * (1.0f / TSEQ);
    __syncthreads();
    float a0 = 0.f, a1 = 0.f, a2 = 0.f;
    for (int s = 0; s < 64; ++s) {
        const ushort* row = G3 + (size_t)(b * TSEQ + s0 + s) * NCAT + 2 * DDIM;
        float w = sr[s];
        a0 += b2f(row[tid])       * w;
        a1 += b2f(row[tid + 256]) * w;
        a2 += b2f(row[tid + 512]) * w;
    }
    atomicAdd(&ybar[b * DDIM + tid],       a0);
    atomicAdd(&ybar[b * DDIM + tid + 256], a1);
    atomicAdd(&ybar[b * DDIM + tid + 512], a2);
}

// ---------------- scores[m] = rw0*un_pot + rw1 * rnx[m]*dot(xe[m], ybar[b]) ----------------
__global__ void pw_scores_k(const ushort* __restrict__ G3, const float* __restrict__ ybar,
                            const float* __restrict__ rnx, const float* __restrict__ un_pot,
                            const float* __restrict__ red_w, float* __restrict__ scores)
{
    int m = blockIdx.x, tid = threadIdx.x;
    int b = m >> 10;
    const ushort* xer = G3 + (size_t)m * NCAT + DDIM;
    const float* yb = ybar + b * DDIM;
    float s = 0.f;
    for (int t = tid; t < DDIM; t += 256) s += b2f(xer[t]) * yb[t];
    for (int off = 32; off; off >>= 1) s += __shfl_down(s, off, 64);
    __shared__ float rb[4];
    int lane = tid & 63, w = tid >> 6;
    if (lane == 0) rb[w] = s;
    __syncthreads();
    if (tid == 0) {
        float dot = rb[0] + rb[1] + rb[2] + rb[3];
        scores[m] = red_w[0] * un_pot[m] + red_w[1] * (rnx[m] * dot);
    }
}

// ---------------- softmax over T per batch ----------------
__global__ void softmax_k(const float* __restrict__ scores, float* __restrict__ wsm)
{
    int b = blockIdx.x, tid = threadIdx.x;
    float v[4];
    float lm = -1e30f;
#pragma unroll
    for (int i = 0; i < 4; ++i) {
        v[i] = scores[b * TSEQ + i * 256 + tid];
        lm = fmaxf(lm, v[i]);
    }
    for (int off = 32; off; off >>= 1) lm = fmaxf(lm, __shfl_down(lm, off, 64));
    __shared__ float rb[4];
    __shared__ float smax, ssum;
    int lane = tid & 63, w = tid >> 6;
    if (lane == 0) rb[w] = lm;
    __syncthreads();
    if (tid == 0) smax = fmaxf(fmaxf(rb[0], rb[1]), fmaxf(rb[2], rb[3]));
    __syncthreads();
    float e[4];
    float ls = 0.f;
#pragma unroll
    for (int i = 0; i < 4; ++i) { e[i] = expf(v[i] - smax); ls += e[i]; }
    for (int off = 32; off; off >>= 1) ls += __shfl_down(ls, off, 64);
    __syncthreads();
    if (lane == 0) rb[w] = ls;
    __syncthreads();
    if (tid == 0) ssum = rb[0] + rb[1] + rb[2] + rb[3];
    __syncthreads();
    float inv = 1.f / ssum;
#pragma unroll
    for (int i = 0; i < 4; ++i) wsm[b * TSEQ + i * 256 + tid] = e[i] * inv;
}

// ---------------- out[b,d] += partial over a 64-step t chunk ----------------
__global__ void out_k(const ushort* __restrict__ U16, const float* __restrict__ wsm,
                      float* __restrict__ out)
{
    int b = blockIdx.x, t0 = blockIdx.y * 64;
    int tid = threadIdx.x;
    __shared__ float sw[64];
    if (tid < 64) sw[tid] = wsm[b * TSEQ + t0 + tid];
    __syncthreads();
    float a0 = 0.f, a1 = 0.f, a2 = 0.f;
    for (int t = 0; t < 64; ++t) {
        const ushort* row = U16 + (size_t)(b * TSEQ + t0 + t) * DDIM;
        float w = sw[t];
        a0 += b2f(row[tid])       * w;
        a1 += b2f(row[tid + 256]) * w;
        a2 += b2f(row[tid + 512]) * w;
    }
    atomicAdd(&out[b * DDIM + tid],       a0);
    atomicAdd(&out[b * DDIM + tid + 256], a1);
    atomicAdd(&out[b * DDIM + tid + 512], a2);
}

// ---------------- workspace layout (bytes) ----------------
// G3 (e|xe|ye bf16, 151 MB) aliases the X16+H16 region (dead after GEMM2).
static const size_t O_X16   = 0;            // 32768*1536*2 = 100663296
static const size_t O_H16   = 100663296;    // 100663296
static const size_t O_G3    = 0;            // 150994944 (alias)
static const size_t O_U16   = 201326592;    // 50331648
static const size_t O_W1    = 251658240;    // 4718592
static const size_t O_W2    = 256376832;    // 2359296
static const size_t O_W3    = 258736128;    // 3538944
static const size_t O_B3    = 262275072;    // 9216
static const size_t O_UNPOT = 262284288;    // 131072
static const size_t O_RNX   = 262415360;    // 131072
static const size_t O_RNY   = 262546432;    // 131072
static const size_t O_SCORE = 262677504;    // 131072
static const size_t O_WSM   = 262808576;    // 131072
static const size_t O_YBAR  = 262939648;    // 98304
// total: 263037952 bytes (~263 MB)

extern "C" void kernel_launch(void* const* d_in, const int* in_sizes, int n_in,
                              void* d_out, int out_size, void* d_ws, size_t ws_size,
                              hipStream_t stream)
{
    const float* x        = (const float*)d_in[0];
    const float* fc1_w    = (const float*)d_in[1];
    const float* fc1_b    = (const float*)d_in[2];
    const float* fc2_w    = (const float*)d_in[3];
    const float* fc2_b    = (const float*)d_in[4];
    const float* un_emb_w = (const float*)d_in[5];
    const float* un_emb_b = (const float*)d_in[6];
    const float* un_red_w = (const float*)d_in[7];
    const float* un_red_b = (const float*)d_in[8];
    const float* pw_x_w   = (const float*)d_in[9];
    const float* pw_x_b   = (const float*)d_in[10];
    const float* pw_y_w   = (const float*)d_in[11];
    const float* pw_y_b   = (const float*)d_in[12];
    const float* red_w    = (const float*)d_in[13];

    char* ws = (char*)d_ws;
    ushort* X16 = (ushort*)(ws + O_X16);
    ushort* H16 = (ushort*)(ws + O_H16);
    ushort* G3  = (ushort*)(ws + O_G3);
    ushort* U16 = (ushort*)(ws + O_U16);
    ushort* W1  = (ushort*)(ws + O_W1);
    ushort* W2  = (ushort*)(ws + O_W2);
    ushort* W3  = (ushort*)(ws + O_W3);
    float*  B3  = (float*)(ws + O_B3);
    float*  UNPOT = (float*)(ws + O_UNPOT);
    float*  RNX = (float*)(ws + O_RNX);
    float*  RNY = (float*)(ws + O_RNY);
    float*  SCORES = (float*)(ws + O_SCORE);
    float*  WSM = (float*)(ws + O_WSM);
    float*  YBAR = (float*)(ws + O_YBAR);

    // --- zero the atomic accumulators (ws/d_out are poisoned 0xAA each call) ---
    hipMemsetAsync(YBAR, 0, BBATCH * DDIM * sizeof(float), stream);
    hipMemsetAsync(d_out, 0, BBATCH * DDIM * sizeof(float), stream);

    // --- convert inputs to bf16 ---
    cvt_bf16<<<49152, 256, 0, stream>>>(x, X16, 12582912);   // 32768*1536/4
    cvt_weights<<<5187, 256, 0, stream>>>(fc1_w, fc2_w, un_emb_w, pw_x_w, pw_y_w,
                                          un_emb_b, pw_x_b, pw_y_b, W1, W2, W3, B3);

    // --- GEMM chain (1-D grid, XCD-pinned swizzle inside kernel) ---
    // h = relu(x @ fc1_w^T + fc1_b)            [M,1536]
    gemm_bt<<<(MROWS / 128) * (INDIM / 128), 256, 0, stream>>>(
        X16, W1, fc1_b, H16, MROWS, INDIM, INDIM, INDIM);
    // u = h @ fc2_w^T + fc2_b                  [M,768]
    gemm_bt<<<(MROWS / 128) * (DDIM / 128), 256, 0, stream>>>(
        H16, W2, fc2_b, U16, MROWS, DDIM, INDIM, 0);
    // [e|xe|ye] = u @ [un_emb|pw_x|pw_y]^T + b  [M,2304], relu on first 768 cols (e)
    gemm_bt<<<(MROWS / 128) * (NCAT / 128), 256, 0, stream>>>(
        U16, W3, B3, G3, MROWS, NCAT, DDIM, DDIM);

    // --- reductions / attention ---
    row_stats_k<<<MROWS, 256, 0, stream>>>(G3, un_red_w, un_red_b, UNPOT, RNX, RNY);
    ybar_k<<<dim3(BBATCH, 16), 256, 0, stream>>>(G3, RNY, YBAR);
    pw_scores_k<<<MROWS, 256, 0, stream>>>(G3, YBAR, RNX, UNPOT, red_w, SCORES);
    softmax_k<<<BBATCH, 256, 0, stream>>>(SCORES, WSM);
    out_k<<<dim3(BBATCH, 16), 256, 0, stream>>>(U16, WSM, (float*)d_out);
}

// Round 6
// 754.014 us; speedup vs baseline: 1.3842x; 1.0020x over previous
//
#include <hip/hip_runtime.h>
#include <stdint.h>

// Problem dims
#define MROWS 32768   // B*T
#define TSEQ  1024
#define BBATCH 32
#define INDIM 1536
#define DDIM  768
#define NCAT  2304    // un_emb (768) + pw_x (768) + pw_y (768)

typedef short short8 __attribute__((ext_vector_type(8)));
typedef short short4v __attribute__((ext_vector_type(4)));
typedef float f32x4  __attribute__((ext_vector_type(4)));

__device__ __forceinline__ float b2f(ushort u) {
    union { uint32_t u; float f; } x; x.u = ((uint32_t)u) << 16; return x.f;
}
__device__ __forceinline__ ushort f2b(float f) {
    union { float f; uint32_t u; } x; x.f = f;
    uint32_t r = x.u + 0x7fffu + ((x.u >> 16) & 1u);
    return (ushort)(r >> 16);
}

// ---------------- fp32 -> bf16 conversion (vectorized x4) ----------------
__global__ void cvt_bf16(const float* __restrict__ in, ushort* __restrict__ out, int n4) {
    int i = blockIdx.x * blockDim.x + threadIdx.x;
    if (i < n4) {
        float4 v = ((const float4*)in)[i];
        ushort4 o;
        o.x = f2b(v.x); o.y = f2b(v.y); o.z = f2b(v.z); o.w = f2b(v.w);
        ((ushort4*)out)[i] = o;
    }
}

__device__ __forceinline__ void cvt4(const float* __restrict__ in, ushort* __restrict__ out, int i) {
    float4 v = ((const float4*)in)[i];
    ushort4 o;
    o.x = f2b(v.x); o.y = f2b(v.y); o.z = f2b(v.z); o.w = f2b(v.w);
    ((ushort4*)out)[i] = o;
}

// All small weight conversions + bias concat + accumulator zeroing in ONE launch.
__global__ void cvt_weights(const float* __restrict__ fc1_w, const float* __restrict__ fc2_w,
                            const float* __restrict__ w3a, const float* __restrict__ w3b,
                            const float* __restrict__ w3c,
                            const float* __restrict__ ba, const float* __restrict__ bb,
                            const float* __restrict__ bc,
                            ushort* __restrict__ W1, ushort* __restrict__ W2,
                            ushort* __restrict__ W3, float* __restrict__ B3,
                            float* __restrict__ ybar_zero, float* __restrict__ out_zero)
{
    int i = blockIdx.x * 256 + threadIdx.x;  // float4 index
    if (i < 589824)        cvt4(fc1_w, W1, i);
    else if (i < 884736)   cvt4(fc2_w, W2, i - 589824);
    else if (i < 1032192)  cvt4(w3a,  W3,           i - 884736);
    else if (i < 1179648)  cvt4(w3b,  W3 + 589824,  i - 1032192);
    else if (i < 1327104)  cvt4(w3c,  W3 + 1179648, i - 1179648);
    else if (i < 1327680) {
        int j = i - 1327104;  // 0..575 float4s of B3 (2304 floats)
        const float* src = (j < 192) ? ba : (j < 384) ? bb : bc;
        int off = (j < 192) ? j : (j < 384) ? (j - 192) : (j - 384);
        ((float4*)B3)[j] = ((const float4*)src)[off];
    }
    else if (i < 1333824) {  // zero YBAR: 32*768 floats = 6144 float4
        float4 z = {0.f, 0.f, 0.f, 0.f};
        ((float4*)ybar_zero)[i - 1327680] = z;
    }
    else if (i < 1339968) {  // zero d_out: 32*768 floats = 6144 float4
        float4 z = {0.f, 0.f, 0.f, 0.f};
        ((float4*)out_zero)[i - 1333824] = z;
    }
}

// ---------------- bf16 GEMM: C[M,N] = A[M,K] * B[N,K]^T + bias, optional relu on cols < relu_ncols
// 128x128 tile / block, 4 waves (2x2), each wave 64x64 = 4x4 MFMA 16x16x32 subtiles.
// BK=64: each staging round covers 32 MFMAs/wave per barrier pair (R5: GEMM1
// 217->177us, MfmaUtil 31->39%). LDS 32 KB keeps occupancy ~4 blocks/CU.
//
// Staging (global_load_lds width=16, LDS dest = base + lane*16B fixed), per
// 16-row x 32-k segment (512 ushorts):
//   lane s -> global (row = s>>2, kb = (s&3) ^ ((s>>3)&3)) of its segment.
//   * 4 consecutive lanes cover one row's full 64 B -> coalesced.
//   * Fragment granule for lane l (r=l&15, q=l>>4): G = 4r + (q ^ ((r>>1)&3));
//     8 consecutive read lanes hit G mod 8 = {0,4,1,5,2,6,3,7} -> conflict-free
//     (R4/R5 measured: SQ_LDS_BANK_CONFLICT = 0).
//
// XCD-pinned swizzle: all ntiles consumers of one A-tile consecutive on ONE XCD.
// Requires (M/128)%8==0, N%128==0, K%64==0.
__global__ __launch_bounds__(256, 2)
void gemm_bt(const ushort* __restrict__ A, const ushort* __restrict__ Bm,
             const float* __restrict__ bias, ushort* __restrict__ C,
             int M, int N, int K, int relu_ncols)
{
    __shared__ __align__(16) ushort lA[128 * 64];  // 16 KB, 16 segments of 16x32
    __shared__ __align__(16) ushort lB[128 * 64];  // 16 KB

    const int tid  = threadIdx.x;
    const int lane = tid & 63, wave = tid >> 6;
    const int wm = wave & 1, wn = wave >> 1;       // 2x2 wave grid
    const int quad = lane >> 4, r16 = lane & 15;

    // XCD-pinned block swizzle
    const int ntiles = N >> 7;
    const int xcd = blockIdx.x & 7;
    const int j   = blockIdx.x >> 3;
    const int g   = j / ntiles;            // m-group within this XCD
    const int n_t = j - g * ntiles;
    const int m_t = xcd + (g << 3);
    const int m0 = m_t * 128, n0 = n_t * 128;

    // staging lane->global map (see header comment)
    const int srow = lane >> 2;
    const int scol = ((lane & 3) ^ ((lane >> 3) & 3)) * 8;
    // fragment-read granule offset (ushorts): (r*4 + (q ^ ((r>>1)&3))) * 8
    const int goff = (r16 << 5) + ((quad ^ ((r16 >> 1) & 3)) << 3);

    f32x4 acc[4][4] = {};

    const int kIters = K >> 6;
    for (int kt = 0; kt < kIters; ++kt) {
        const int k0 = kt << 6;
        __syncthreads();   // previous round's LDS reads complete
#pragma unroll
        for (int c = 0; c < 4; ++c) {
            int S  = wave * 4 + c;
            int kh = S >> 3, rs = S & 7;
            int row = rs * 16 + srow;
            int kc  = k0 + kh * 32 + scol;
            const ushort* ga = A + (size_t)(m0 + row) * K + kc;
            __builtin_amdgcn_global_load_lds(
                (const __attribute__((address_space(1))) void*)ga,
                (__attribute__((address_space(3))) void*)&lA[S * 512], 16, 0, 0);
            const ushort* gb = Bm + (size_t)(n0 + row) * K + kc;
            __builtin_amdgcn_global_load_lds(
                (const __attribute__((address_space(1))) void*)gb,
                (__attribute__((address_space(3))) void*)&lB[S * 512], 16, 0, 0);
        }
        __syncthreads();   // staging complete

#pragma unroll
        for (int kh = 0; kh < 2; ++kh) {
            short8 af[4], bf[4];
#pragma unroll
            for (int i = 0; i < 4; ++i)
                af[i] = *(const short8*)&lA[kh * 4096 + (wm * 4 + i) * 512 + goff];
#pragma unroll
            for (int j2 = 0; j2 < 4; ++j2)
                bf[j2] = *(const short8*)&lB[kh * 4096 + (wn * 4 + j2) * 512 + goff];
#pragma unroll
            for (int i = 0; i < 4; ++i)
#pragma unroll
                for (int j2 = 0; j2 < 4; ++j2)
                    acc[i][j2] = __builtin_amdgcn_mfma_f32_16x16x32_bf16(af[i], bf[j2], acc[i][j2], 0, 0, 0);
        }
    }

    // epilogue: C/D layout col = lane&15, row = quad*4 + reg  [m89-verified]
#pragma unroll
    for (int j2 = 0; j2 < 4; ++j2) {
        int gn = n0 + wn * 64 + j2 * 16 + r16;
        float bv = bias[gn];
        bool dorelu = gn < relu_ncols;
#pragma unroll
        for (int i = 0; i < 4; ++i) {
            int gmb = m0 + wm * 64 + i * 16 + quad * 4;
#pragma unroll
            for (int rr = 0; rr < 4; ++rr) {
                float v = acc[i][j2][rr] + bv;
                if (dorelu) v = fmaxf(v, 0.f);
                C[(size_t)(gmb + rr) * N + gn] = f2b(v);
            }
        }
    }
}

// ---------------- per-row raw sums over G3=[M,2304] (e | xe | ye), bf16 ----------------
// sums: se[m] = sum(e*urw)  (no urb);  sx[m] = sum(xe^2);  sy[m] = sum(ye^2).
// ushort8 (16B) loads: 288 chunks of 8 per row; chunk c: section c/96 (0=e,1=x,2=y).
__global__ void row_stats_k(const ushort* __restrict__ G3, const float* __restrict__ urw,
                            float* __restrict__ se_o, float* __restrict__ sx_o,
                            float* __restrict__ sy_o)
{
    int m = blockIdx.x, tid = threadIdx.x;
    const ushort* row = G3 + (size_t)m * NCAT;
    float se = 0.f, sx = 0.f, sy = 0.f;
    for (int c = tid; c < 288; c += 256) {
        short8 v = *(const short8*)(row + c * 8);
        if (c < 96) {
            const float4 u0 = ((const float4*)urw)[c * 2];
            const float4 u1 = ((const float4*)urw)[c * 2 + 1];
            se += b2f((ushort)v[0]) * u0.x + b2f((ushort)v[1]) * u0.y
                + b2f((ushort)v[2]) * u0.z + b2f((ushort)v[3]) * u0.w
                + b2f((ushort)v[4]) * u1.x + b2f((ushort)v[5]) * u1.y
                + b2f((ushort)v[6]) * u1.z + b2f((ushort)v[7]) * u1.w;
        } else {
            float a = 0.f;
#pragma unroll
            for (int k = 0; k < 8; ++k) { float f = b2f((ushort)v[k]); a += f * f; }
            if (c < 192) sx += a; else sy += a;
        }
    }
    for (int off = 32; off; off >>= 1) {
        se += __shfl_down(se, off, 64);
        sx += __shfl_down(sx, off, 64);
        sy += __shfl_down(sy, off, 64);
    }
    __shared__ float rb[3][4];
    int lane = tid & 63, w = tid >> 6;
    if (lane == 0) { rb[0][w] = se; rb[1][w] = sx; rb[2][w] = sy; }
    __syncthreads();
    if (tid == 0) {
        se_o[m] = rb[0][0] + rb[0][1] + rb[0][2] + rb[0][3];
        sx_o[m] = rb[1][0] + rb[1][1] + rb[1][2] + rb[1][3];
        sy_o[m] = rb[2][0] + rb[2][1] + rb[2][2] + rb[2][3];
    }
}

// ---------------- ybar[b,d] += partial over a 32-step s chunk ----------------
// ybar[b,d] = (1/T) * sum_s ye[b,s,d] / max(||ye[b,s]||,1e-12); grid (B, 32).
__global__ void ybar_k(const ushort* __restrict__ G3, const float* __restrict__ sy,
                       float* __restrict__ ybar)
{
    int b = blockIdx.x, s0 = blockIdx.y * 32;
    int tid = threadIdx.x;
    __shared__ float sr[32];
    if (tid < 32) {
        float v = sy[b * TSEQ + s0 + tid];
        sr[tid] = (1.0f / TSEQ) / fmaxf(sqrtf(v), 1e-12f);
    }
    __syncthreads();
    float a0 = 0.f, a1 = 0.f, a2 = 0.f;
#pragma unroll 8
    for (int s = 0; s < 32; ++s) {
        const ushort* row = G3 + (size_t)(b * TSEQ + s0 + s) * NCAT + 2 * DDIM;
        float w = sr[s];
        a0 += b2f(row[tid])       * w;
        a1 += b2f(row[tid + 256]) * w;
        a2 += b2f(row[tid + 512]) * w;
    }
    atomicAdd(&ybar[b * DDIM + tid],       a0);
    atomicAdd(&ybar[b * DDIM + tid + 256], a1);
    atomicAdd(&ybar[b * DDIM + tid + 512], a2);
}

// ---------------- scores[m] = rw0*(se+urb) + rw1 * dot(xe[m],ybar[b]) / max(||xe||,1e-12) ----
__global__ void pw_scores_k(const ushort* __restrict__ G3, const float* __restrict__ ybar,
                            const float* __restrict__ se_i, const float* __restrict__ sx_i,
                            const float* __restrict__ urb, const float* __restrict__ red_w,
                            float* __restrict__ scores)
{
    int m = blockIdx.x, tid = threadIdx.x;
    int b = m >> 10;
    float s = 0.f;
    if (tid < 192) {   // 192 ushort4 chunks cover xe's 768 cols
        short4v v = *(const short4v*)(G3 + (size_t)m * NCAT + DDIM + tid * 4);
        float4 yv = ((const float4*)(ybar + b * DDIM))[tid];
        s = b2f((ushort)v[0]) * yv.x + b2f((ushort)v[1]) * yv.y
          + b2f((ushort)v[2]) * yv.z + b2f((ushort)v[3]) * yv.w;
    }
    for (int off = 32; off; off >>= 1) s += __shfl_down(s, off, 64);
    __shared__ float rb[4];
    int lane = tid & 63, w = tid >> 6;
    if (lane == 0) rb[w] = s;
    __syncthreads();
    if (tid == 0) {
        float dot = rb[0] + rb[1] + rb[2] + rb[3];
        float rnx = 1.f / fmaxf(sqrtf(sx_i[m]), 1e-12f);
        float un_pot = se_i[m] + urb[0];
        scores[m] = red_w[0] * un_pot + red_w[1] * (rnx * dot);
    }
}

// ---------------- softmax over T per batch ----------------
__global__ void softmax_k(const float* __restrict__ scores, float* __restrict__ wsm)
{
    int b = blockIdx.x, tid = threadIdx.x;
    float v[4];
    float lm = -1e30f;
#pragma unroll
    for (int i = 0; i < 4; ++i) {
        v[i] = scores[b * TSEQ + i * 256 + tid];
        lm = fmaxf(lm, v[i]);
    }
    for (int off = 32; off; off >>= 1) lm = fmaxf(lm, __shfl_down(lm, off, 64));
    __shared__ float rb[4];
    __shared__ float smax, ssum;
    int lane = tid & 63, w = tid >> 6;
    if (lane == 0) rb[w] = lm;
    __syncthreads();
    if (tid == 0) smax = fmaxf(fmaxf(rb[0], rb[1]), fmaxf(rb[2], rb[3]));
    __syncthreads();
    float e[4];
    float ls = 0.f;
#pragma unroll
    for (int i = 0; i < 4; ++i) { e[i] = expf(v[i] - smax); ls += e[i]; }
    for (int off = 32; off; off >>= 1) ls += __shfl_down(ls, off, 64);
    __syncthreads();
    if (lane == 0) rb[w] = ls;
    __syncthreads();
    if (tid == 0) ssum = rb[0] + rb[1] + rb[2] + rb[3];
    __syncthreads();
    float inv = 1.f / ssum;
#pragma unroll
    for (int i = 0; i < 4; ++i) wsm[b * TSEQ + i * 256 + tid] = e[i] * inv;
}

// ---------------- out[b,d] += partial over a 32-step t chunk ----------------
__global__ void out_k(const ushort* __restrict__ U16, const float* __restrict__ wsm,
                      float* __restrict__ out)
{
    int b = blockIdx.x, t0 = blockIdx.y * 32;
    int tid = threadIdx.x;
    __shared__ float sw[32];
    if (tid < 32) sw[tid] = wsm[b * TSEQ + t0 + tid];
    __syncthreads();
    float a0 = 0.f, a1 = 0.f, a2 = 0.f;
#pragma unroll 8
    for (int t = 0; t < 32; ++t) {
        const ushort* row = U16 + (size_t)(b * TSEQ + t0 + t) * DDIM;
        float w = sw[t];
        a0 += b2f(row[tid])       * w;
        a1 += b2f(row[tid + 256]) * w;
        a2 += b2f(row[tid + 512]) * w;
    }
    atomicAdd(&out[b * DDIM + tid],       a0);
    atomicAdd(&out[b * DDIM + tid + 256], a1);
    atomicAdd(&out[b * DDIM + tid + 512], a2);
}

// ---------------- workspace layout (bytes) ----------------
// G3 (e|xe|ye bf16, 151 MB) aliases the X16+H16 region (dead after GEMM2).
static const size_t O_X16   = 0;            // 32768*1536*2 = 100663296
static const size_t O_H16   = 100663296;    // 100663296
static const size_t O_G3    = 0;            // 150994944 (alias)
static const size_t O_U16   = 201326592;    // 50331648
static const size_t O_W1    = 251658240;    // 4718592
static const size_t O_W2    = 256376832;    // 2359296
static const size_t O_W3    = 258736128;    // 3538944
static const size_t O_B3    = 262275072;    // 9216
static const size_t O_SE    = 262284288;    // 131072
static const size_t O_SX    = 262415360;    // 131072
static const size_t O_SY    = 262546432;    // 131072
static const size_t O_SCORE = 262677504;    // 131072
static const size_t O_WSM   = 262808576;    // 131072
static const size_t O_YBAR  = 262939648;    // 98304
// total: 263037952 bytes (~263 MB)

extern "C" void kernel_launch(void* const* d_in, const int* in_sizes, int n_in,
                              void* d_out, int out_size, void* d_ws, size_t ws_size,
                              hipStream_t stream)
{
    const float* x        = (const float*)d_in[0];
    const float* fc1_w    = (const float*)d_in[1];
    const float* fc1_b    = (const float*)d_in[2];
    const float* fc2_w    = (const float*)d_in[3];
    const float* fc2_b    = (const float*)d_in[4];
    const float* un_emb_w = (const float*)d_in[5];
    const float* un_emb_b = (const float*)d_in[6];
    const float* un_red_w = (const float*)d_in[7];
    const float* un_red_b = (const float*)d_in[8];
    const float* pw_x_w   = (const float*)d_in[9];
    const float* pw_x_b   = (const float*)d_in[10];
    const float* pw_y_w   = (const float*)d_in[11];
    const float* pw_y_b   = (const float*)d_in[12];
    const float* red_w    = (const float*)d_in[13];

    char* ws = (char*)d_ws;
    ushort* X16 = (ushort*)(ws + O_X16);
    ushort* H16 = (ushort*)(ws + O_H16);
    ushort* G3  = (ushort*)(ws + O_G3);
    ushort* U16 = (ushort*)(ws + O_U16);
    ushort* W1  = (ushort*)(ws + O_W1);
    ushort* W2  = (ushort*)(ws + O_W2);
    ushort* W3  = (ushort*)(ws + O_W3);
    float*  B3  = (float*)(ws + O_B3);
    float*  SE  = (float*)(ws + O_SE);
    float*  SX  = (float*)(ws + O_SX);
    float*  SY  = (float*)(ws + O_SY);
    float*  SCORES = (float*)(ws + O_SCORE);
    float*  WSM = (float*)(ws + O_WSM);
    float*  YBAR = (float*)(ws + O_YBAR);

    // --- convert inputs to bf16; also zeros YBAR and d_out (poisoned 0xAA) ---
    cvt_bf16<<<49152, 256, 0, stream>>>(x, X16, 12582912);   // 32768*1536/4
    cvt_weights<<<5235, 256, 0, stream>>>(fc1_w, fc2_w, un_emb_w, pw_x_w, pw_y_w,
                                          un_emb_b, pw_x_b, pw_y_b, W1, W2, W3, B3,
                                          YBAR, (float*)d_out);

    // --- GEMM chain (1-D grid, XCD-pinned swizzle inside kernel) ---
    // h = relu(x @ fc1_w^T + fc1_b)            [M,1536]
    gemm_bt<<<(MROWS / 128) * (INDIM / 128), 256, 0, stream>>>(
        X16, W1, fc1_b, H16, MROWS, INDIM, INDIM, INDIM);
    // u = h @ fc2_w^T + fc2_b                  [M,768]
    gemm_bt<<<(MROWS / 128) * (DDIM / 128), 256, 0, stream>>>(
        H16, W2, fc2_b, U16, MROWS, DDIM, INDIM, 0);
    // [e|xe|ye] = u @ [un_emb|pw_x|pw_y]^T + b  [M,2304], relu on first 768 cols (e)
    gemm_bt<<<(MROWS / 128) * (NCAT / 128), 256, 0, stream>>>(
        U16, W3, B3, G3, MROWS, NCAT, DDIM, DDIM);

    // --- reductions / attention ---
    row_stats_k<<<MROWS, 256, 0, stream>>>(G3, un_red_w, SE, SX, SY);
    ybar_k<<<dim3(BBATCH, 32), 256, 0, stream>>>(G3, SY, YBAR);
    pw_scores_k<<<MROWS, 256, 0, stream>>>(G3, YBAR, SE, SX, un_red_b, red_w, SCORES);
    softmax_k<<<BBATCH, 256, 0, stream>>>(SCORES, WSM);
    out_k<<<dim3(BBATCH, 32), 256, 0, stream>>>(U16, WSM, (float*)d_out);
}